// Round 10
// baseline (175.100 us; speedup 1.0000x reference)
//
#include <hip/hip_runtime.h>
#include <hip/hip_bf16.h>
#include <math.h>

#define NN4   4096
#define QSCALE 0.180336880111120420f   // 0.125 * log2(e); exp(S/8)=exp2(S*QSCALE)

typedef __attribute__((ext_vector_type(8))) short short8;
typedef __attribute__((ext_vector_type(8))) unsigned short ushort8;
typedef __attribute__((ext_vector_type(4))) unsigned short ushort4v;
typedef __attribute__((ext_vector_type(4))) float f32x4;

__device__ __forceinline__ unsigned short f2b(float f) {
  union { __hip_bfloat16 h; unsigned short u; } v;
  v.h = __float2bfloat16(f);
  return v.u;
}
__device__ __forceinline__ float b2f(unsigned short s) {
  return __uint_as_float(((unsigned int)s) << 16);
}
__device__ __forceinline__ ushort8 cvt8(f32x4 a, f32x4 b) {
  return (ushort8){f2b(a[0]), f2b(a[1]), f2b(a[2]), f2b(a[3]),
                   f2b(b[0]), f2b(b[1]), f2b(b[2]), f2b(b[3])};
}

#define GLOAD16(gp, lp) __builtin_amdgcn_global_load_lds( \
    (const __attribute__((address_space(1))) void*)(gp),  \
    (__attribute__((address_space(3))) void*)(lp), 16, 0, 0)

// ---------------- row normalize (mean/std over 512, ddof=1) -> bf16 ----------------
__global__ __launch_bounds__(256) void k_norm(const float* __restrict__ x,
                                              unsigned short* __restrict__ y) {
  int row  = blockIdx.x * 4 + (threadIdx.x >> 6);
  int lane = threadIdx.x & 63;
  const float4* src = (const float4*)(x + (size_t)row * 512);
  float4 a = src[lane];
  float4 b = src[lane + 64];
  float s = a.x + a.y + a.z + a.w + b.x + b.y + b.z + b.w;
#pragma unroll
  for (int off = 32; off; off >>= 1) s += __shfl_xor(s, off);
  float mean = s * (1.0f / 512.0f);
  float ssq = 0.f, d;
  d = a.x - mean; ssq += d * d;  d = a.y - mean; ssq += d * d;
  d = a.z - mean; ssq += d * d;  d = a.w - mean; ssq += d * d;
  d = b.x - mean; ssq += d * d;  d = b.y - mean; ssq += d * d;
  d = b.z - mean; ssq += d * d;  d = b.w - mean; ssq += d * d;
#pragma unroll
  for (int off = 32; off; off >>= 1) ssq += __shfl_xor(ssq, off);
  float inv = 1.0f / (sqrtf(ssq * (1.0f / 511.0f)) + 1e-9f);
  unsigned short* dst = y + (size_t)row * 512;
  ushort4v va = (ushort4v){f2b((a.x - mean) * inv), f2b((a.y - mean) * inv),
                           f2b((a.z - mean) * inv), f2b((a.w - mean) * inv)};
  ushort4v vb = (ushort4v){f2b((b.x - mean) * inv), f2b((b.y - mean) * inv),
                           f2b((b.z - mean) * inv), f2b((b.w - mean) * inv)};
  *(ushort4v*)(dst + lane * 4)       = va;
  *(ushort4v*)(dst + 256 + lane * 4) = vb;
}

// ---------------- counting f32 -> bf16 copy (one-time) ----------------
__global__ __launch_bounds__(256) void k_cvtcnt(const float* __restrict__ in,
                                                unsigned short* __restrict__ out) {
  size_t i = ((size_t)blockIdx.x * 256 + threadIdx.x) * 8;
  const size_t stride = (size_t)gridDim.x * 256 * 8;
  for (; i < (size_t)4096 * 4096; i += stride) {
    f32x4 a = *(const f32x4*)(in + i);
    f32x4 b = *(const f32x4*)(in + i + 4);
    *(ushort8*)(out + i) = cvt8(a, b);
  }
}

// ----------- fused Q/K/V projection: C = A[4096,K] @ W[N,K]^T -----------
__global__ __launch_bounds__(256) void k_projqkv(
    const unsigned short* __restrict__ Ap, int K,
    const float* __restrict__ Wq, const float* __restrict__ Wk,
    const float* __restrict__ Wv, int N, int nT,
    unsigned short* __restrict__ Qo, unsigned short* __restrict__ Ko,
    unsigned short* __restrict__ VT, int padrows, float qscale) {
  __shared__ unsigned short As[128 * 40];
  __shared__ unsigned short Bs[128 * 40];
  const int tid = threadIdx.x;
  const int sel = blockIdx.y / nT;
  const int n0 = (blockIdx.y % nT) * 128;
  const int m0 = blockIdx.x * 128;
  const float* Bp = sel == 0 ? Wq : (sel == 1 ? Wk : Wv);
  const float bscale = sel == 0 ? qscale : 1.0f;
  const int lane = tid & 63, wid = tid >> 6;
  const int hi = lane >> 4, lo = lane & 15;
  const int wr = (wid >> 1) << 6, wc = (wid & 1) << 6;
  const int srow = tid >> 1, sk = (tid & 1) << 4;
  f32x4 acc[4][4];
#pragma unroll
  for (int i = 0; i < 4; ++i)
#pragma unroll
    for (int j = 0; j < 4; ++j) acc[i][j] = (f32x4){0.f, 0.f, 0.f, 0.f};

  for (int k0 = 0; k0 < K; k0 += 32) {
    ushort8 va0, va1, vb0, vb1;
    {
      const unsigned short* s = Ap + (size_t)(m0 + srow) * K + k0 + sk;
      va0 = *(const ushort8*)(s);
      va1 = *(const ushort8*)(s + 8);
    }
    {
      int gr = n0 + srow;
      if (gr < N) {
        const float* s = Bp + (size_t)gr * K + k0 + sk;
        f32x4 f0 = *(const f32x4*)(s) * bscale;
        f32x4 f1 = *(const f32x4*)(s + 4) * bscale;
        f32x4 f2 = *(const f32x4*)(s + 8) * bscale;
        f32x4 f3 = *(const f32x4*)(s + 12) * bscale;
        vb0 = cvt8(f0, f1); vb1 = cvt8(f2, f3);
      } else { vb0 = (ushort8)0; vb1 = (ushort8)0; }
    }
    __syncthreads();
    *(ushort8*)&As[srow * 40 + sk]     = va0;
    *(ushort8*)&As[srow * 40 + sk + 8] = va1;
    *(ushort8*)&Bs[srow * 40 + sk]     = vb0;
    *(ushort8*)&Bs[srow * 40 + sk + 8] = vb1;
    __syncthreads();
    short8 af[4], bf[4];
#pragma unroll
    for (int i = 0; i < 4; ++i)
      af[i] = *(const short8*)&As[(wr + (i << 4) + lo) * 40 + hi * 8];
#pragma unroll
    for (int j = 0; j < 4; ++j)
      bf[j] = *(const short8*)&Bs[(wc + (j << 4) + lo) * 40 + hi * 8];
#pragma unroll
    for (int i = 0; i < 4; ++i)
#pragma unroll
      for (int j = 0; j < 4; ++j)
        acc[i][j] = __builtin_amdgcn_mfma_f32_16x16x32_bf16(af[i], bf[j], acc[i][j], 0, 0, 0);
  }

  if (sel < 2) {
    unsigned short* Cp = sel == 0 ? Qo : Ko;
#pragma unroll
    for (int i = 0; i < 4; ++i)
#pragma unroll
      for (int j = 0; j < 4; ++j)
#pragma unroll
        for (int reg = 0; reg < 4; ++reg) {
          int r = m0 + wr + (i << 4) + (hi << 2) + reg;
          int c = n0 + wc + (j << 4) + lo;
          if (c < N) Cp[(size_t)r * N + c] = f2b(acc[i][j][reg]);
        }
  } else {
#pragma unroll
    for (int i = 0; i < 4; ++i)
#pragma unroll
      for (int j = 0; j < 4; ++j) {
        int c = n0 + wc + (j << 4) + lo;
        if (c < N) {
          int hh = c >> 6, dd = c & 63;
          int rb = m0 + wr + (i << 4) + (hi << 2);
          ushort4v pk = (ushort4v){f2b(acc[i][j][0]), f2b(acc[i][j][1]),
                                   f2b(acc[i][j][2]), f2b(acc[i][j][3])};
          *(ushort4v*)&VT[(size_t)(hh * 68 + dd) * NN4 + rb] = pk;
        }
      }
    int hstart = n0 >> 6;
    int hcnt = (N - n0) >> 6; if (hcnt > 2) hcnt = 2;
    int tot = hcnt * padrows * 128;
    for (int e = tid; e < tot; e += 256) {
      int hh = hstart + e / (padrows * 128);
      int rem = e % (padrows * 128);
      int j = rem >> 7, col = m0 + (rem & 127);
      VT[(size_t)(hh * 68 + 64 + j) * NN4 + col] = (j == 0) ? 0x3F80 : 0;
    }
  }
}

// --------- CVX split-K (m97 structure): Pb[z][4096][NF*16] = cntB-slice @ Bt^T ---------
// Both operands bf16 via global_load_lds, double-buffered; A read-side swizzle
// row*64 + (hi^((row>>1)&3))*16 paired with the same permutation on the source.
template<int NF, int MINW>
__global__ __launch_bounds__(256, MINW) void k_cvxg(
    const unsigned short* __restrict__ cntB,
    const unsigned short* __restrict__ Bt,     // [NF*16][4096] bf16
    unsigned short* __restrict__ Pb) {
  constexpr int LDB = NF * 16;
  __shared__ unsigned short As[2][4096];       // 128 rows x 32 k (swizzled slots)
  __shared__ unsigned short Bs[2][NF * 512];
  const int tid = threadIdx.x, lane = tid & 63, wid = tid >> 6;
  const int hi = lane >> 4, lo = lane & 15;
  const int m0 = blockIdx.x * 128;
  const int kbeg = blockIdx.y << 8, kend = kbeg + 256;
  const int boff = (lo * 64 + hi * 16) ^ (((lo >> 1) & 3) << 4);   // B read (bytes)

  f32x4 acc[2][NF];
#pragma unroll
  for (int i = 0; i < 2; ++i)
#pragma unroll
    for (int j = 0; j < NF; ++j) acc[i][j] = (f32x4){0.f, 0.f, 0.f, 0.f};

  auto STAGE = [&](int k0, int buf) {
    // A: 8 chunks of 1KB; wave wid takes chunks wid and 4+wid.
#pragma unroll
    for (int s = 0; s < 2; ++s) {
      int ch = s * 4 + wid;
      int row = ch * 16 + (lane >> 2);
      int hia = (lane & 3) ^ ((row >> 1) & 3);
      GLOAD16(cntB + (size_t)(m0 + row) * 4096 + k0 + hia * 8,
              (char*)&As[buf][0] + ch * 1024);
    }
    // B: NF chunks of 1KB with source-side XOR swizzle.
    for (int c = wid; c < NF; c += 4) {
      int P = c * 1024 + lane * 16;
      int L = P ^ ((P >> 3) & 0x30);
      GLOAD16(Bt + (size_t)(L >> 6) * 4096 + k0 + ((L & 63) >> 1),
              (char*)&Bs[buf][0] + c * 1024);
    }
  };

  STAGE(kbeg, 0);
  asm volatile("s_waitcnt vmcnt(0)" ::: "memory");
  __syncthreads();

  const int r0 = 32 * wid + lo, r1 = r0 + 16;
  const int ho = ((hi ^ ((r0 >> 1) & 3)) << 3);    // shared by r0,r1 ((x+16)>>1 keeps &3)

  for (int k0 = kbeg; k0 < kend; k0 += 32) {
    const int cur = ((k0 - kbeg) >> 5) & 1, nxt = cur ^ 1;
    if (k0 + 32 < kend) STAGE(k0 + 32, nxt);       // loads fly under MFMA
    short8 af0 = *(const short8*)&As[cur][r0 * 32 + ho];
    short8 af1 = *(const short8*)&As[cur][r1 * 32 + ho];
    __builtin_amdgcn_s_setprio(1);
#pragma unroll
    for (int j = 0; j < NF; ++j) {
      short8 bf = *(const short8*)((const char*)&Bs[cur][0] + j * 1024 + boff);
      acc[0][j] = __builtin_amdgcn_mfma_f32_16x16x32_bf16(af0, bf, acc[0][j], 0, 0, 0);
      acc[1][j] = __builtin_amdgcn_mfma_f32_16x16x32_bf16(af1, bf, acc[1][j], 0, 0, 0);
    }
    __builtin_amdgcn_s_setprio(0);
    asm volatile("s_waitcnt vmcnt(0)" ::: "memory");
    __syncthreads();
  }
  unsigned short* P = Pb + (size_t)blockIdx.y * 4096 * LDB;
#pragma unroll
  for (int i = 0; i < 2; ++i)
#pragma unroll
    for (int j = 0; j < NF; ++j)
#pragma unroll
      for (int reg = 0; reg < 4; ++reg) {
        int r = m0 + 32 * wid + 16 * i + 4 * hi + reg;
        P[(size_t)r * LDB + 16 * j + lo] = f2b(acc[i][j][reg]);
      }
}

// ---------- reduce bf16 split-K partials + transpose -> bf16 [orow][4096] ----------
__global__ __launch_bounds__(256) void k_tredB(const unsigned short* __restrict__ in, int ld,
                                               int nsl, unsigned short* __restrict__ out,
                                               int orow) {
  __shared__ float t[64][65];
  const int n0 = blockIdx.x << 6, d0 = blockIdx.y << 6;
  const int o  = threadIdx.x & 7;
  const int rr = threadIdx.x >> 3;
  const size_t pstride = (size_t)4096 * ld;
  const bool valid = (o * 8) < (ld - d0);
#pragma unroll
  for (int pass = 0; pass < 2; ++pass) {
    const int r = rr + (pass << 5);
    float a[8] = {0.f, 0.f, 0.f, 0.f, 0.f, 0.f, 0.f, 0.f};
    if (valid) {
      const unsigned short* p = in + (size_t)(n0 + r) * ld + d0 + o * 8;
      for (int z = 0; z < nsl; ++z) {
        ushort8 v = *(const ushort8*)(p + (size_t)z * pstride);
#pragma unroll
        for (int k = 0; k < 8; ++k) a[k] += b2f(v[k]);
      }
    }
#pragma unroll
    for (int k = 0; k < 8; ++k) t[o * 8 + k][r] = a[k];
  }
  __syncthreads();
  const int c = threadIdx.x & 63, r4 = threadIdx.x >> 6;
#pragma unroll
  for (int i = 0; i < 16; ++i) {
    int dr = r4 + (i << 2);
    if (d0 + dr < orow)
      out[(size_t)(d0 + dr) * 4096 + n0 + c] = f2b(t[dr][c]);
  }
}

// ---------------- fused GKAT attention: num = exp2(Q K^T) @ CVX^T ----------------
__global__ __launch_bounds__(256, 2) void k_attn(
    const unsigned short* __restrict__ Qg, const unsigned short* __restrict__ Kg,
    int ldqk, const unsigned short* __restrict__ CVg,
    unsigned short* __restrict__ Pb) {
  __shared__ unsigned short Ks[128 * 72];
  __shared__ unsigned short Cs[80 * 136];
  __shared__ unsigned short Es[128 * 136];     // byte ^= (row&7)<<5 swizzle
  const int tid = threadIdx.x, lane = tid & 63, wid = tid >> 6;
  const int hi = lane >> 4, lo = lane & 15;
  const int qb = blockIdx.x, h = blockIdx.y, sl = blockIdx.z;
  const int n0 = qb * 128;
  const int MS = 4096 / gridDim.z;
  const int m0beg = sl * MS;
  const int wr = (wid >> 1) << 6, wc = (wid & 1) << 6;

  short8 qf[4][2];
  const unsigned short* Qh = Qg + (size_t)h * 64;
#pragma unroll
  for (int j = 0; j < 4; ++j)
#pragma unroll
    for (int t = 0; t < 2; ++t)
      qf[j][t] = *(const short8*)(Qh + (size_t)(n0 + wc + 16 * j + lo) * ldqk + t * 32 + hi * 8);

  const unsigned short* CVh = CVg + (size_t)h * 68 * NN4;
  const unsigned short* Kh  = Kg + (size_t)h * 64;

  const int krow = tid >> 1, khalf = (tid & 1) << 5;
  int crdR[5], crdW[5], ccol[5];
#pragma unroll
  for (int k = 0; k < 5; ++k) {
    int c = tid + k * 256;
    int row = c >> 4;
    crdW[k] = row;
    crdR[k] = row < 68 ? row : 67;
    ccol[k] = (c & 15) << 3;
  }
  ushort8 krg[4], crg[5];

  auto LOADK = [&](int m0) {
    const unsigned short* src = Kh + (size_t)(m0 + krow) * ldqk + khalf;
    krg[0] = *(const ushort8*)(src);
    krg[1] = *(const ushort8*)(src + 8);
    krg[2] = *(const ushort8*)(src + 16);
    krg[3] = *(const ushort8*)(src + 24);
  };
  auto LOADC = [&](int m0) {
#pragma unroll
    for (int k = 0; k < 5; ++k)
      crg[k] = *(const ushort8*)(CVh + (size_t)crdR[k] * NN4 + m0 + ccol[k]);
  };
  auto WRITEK = [&]() {
    unsigned short* dp = &Ks[krow * 72 + khalf];
    *(ushort8*)(dp) = krg[0];      *(ushort8*)(dp + 8) = krg[1];
    *(ushort8*)(dp + 16) = krg[2]; *(ushort8*)(dp + 24) = krg[3];
  };
  auto WRITEC = [&]() {
#pragma unroll
    for (int k = 0; k < 5; ++k)
      *(ushort8*)&Cs[crdW[k] * 136 + ccol[k]] = crg[k];
  };

  f32x4 accn[2][5];
#pragma unroll
  for (int i = 0; i < 2; ++i)
#pragma unroll
    for (int j = 0; j < 5; ++j) accn[i][j] = (f32x4){0.f, 0.f, 0.f, 0.f};

  LOADK(m0beg); LOADC(m0beg);
  WRITEK(); WRITEC();
  __syncthreads();

  for (int mt = 0; mt < MS; mt += 128) {
    const int m0 = m0beg + mt;
    const bool more = (mt + 128) < MS;
    if (more) { LOADK(m0 + 128); LOADC(m0 + 128); }
    short8 kf[4][2];
#pragma unroll
    for (int i = 0; i < 4; ++i)
#pragma unroll
      for (int t = 0; t < 2; ++t)
        kf[i][t] = *(const short8*)&Ks[(wr + 16 * i + lo) * 72 + t * 32 + hi * 8];
    f32x4 s[4][4];
#pragma unroll
    for (int i = 0; i < 4; ++i)
#pragma unroll
      for (int j = 0; j < 4; ++j) s[i][j] = (f32x4){0.f, 0.f, 0.f, 0.f};
    __builtin_amdgcn_s_setprio(1);
#pragma unroll
    for (int t = 0; t < 2; ++t)
#pragma unroll
      for (int i = 0; i < 4; ++i)
#pragma unroll
        for (int j = 0; j < 4; ++j)
          s[i][j] = __builtin_amdgcn_mfma_f32_16x16x32_bf16(kf[i][t], qf[j][t], s[i][j], 0, 0, 0);
    __builtin_amdgcn_s_setprio(0);
#pragma unroll
    for (int i = 0; i < 4; ++i)
#pragma unroll
      for (int j = 0; j < 4; ++j) {
        unsigned int u0 = (unsigned int)f2b(__builtin_amdgcn_exp2f(s[i][j][0])) |
                          ((unsigned int)f2b(__builtin_amdgcn_exp2f(s[i][j][1])) << 16);
        unsigned int u1 = (unsigned int)f2b(__builtin_amdgcn_exp2f(s[i][j][2])) |
                          ((unsigned int)f2b(__builtin_amdgcn_exp2f(s[i][j][3])) << 16);
        unsigned long long pk = (unsigned long long)u0 | ((unsigned long long)u1 << 32);
        int row = wc + 16 * j + lo;
        int byte = row * 272 + (wr + 16 * i + 4 * hi) * 2;
        *(unsigned long long*)((char*)Es + (byte ^ ((row & 7) << 5))) = pk;
      }
    __syncthreads();
    if (more) WRITEK();
    __builtin_amdgcn_s_setprio(1);
#pragma unroll
    for (int t2 = 0; t2 < 4; ++t2) {
      int r0 = 32 * wid + lo, r1 = r0 + 16;
      int cb = (t2 * 32 + hi * 8) * 2;
      short8 ea0 = *(const short8*)((const char*)Es + ((r0 * 272 + cb) ^ ((r0 & 7) << 5)));
      short8 ea1 = *(const short8*)((const char*)Es + ((r1 * 272 + cb) ^ ((r1 & 7) << 5)));
      short8 cbv[5];
#pragma unroll
      for (int j2 = 0; j2 < 5; ++j2)
        cbv[j2] = *(const short8*)&Cs[(16 * j2 + lo) * 136 + t2 * 32 + hi * 8];
#pragma unroll
      for (int j2 = 0; j2 < 5; ++j2) {
        accn[0][j2] = __builtin_amdgcn_mfma_f32_16x16x32_bf16(ea0, cbv[j2], accn[0][j2], 0, 0, 0);
        accn[1][j2] = __builtin_amdgcn_mfma_f32_16x16x32_bf16(ea1, cbv[j2], accn[1][j2], 0, 0, 0);
      }
    }
    __builtin_amdgcn_s_setprio(0);
    __syncthreads();
    if (more) { WRITEC(); __syncthreads(); }
  }
  unsigned short* P = Pb + (((size_t)h * gridDim.x + qb) * gridDim.z + sl) * (128 * 80);
#pragma unroll
  for (int i2 = 0; i2 < 2; ++i2)
#pragma unroll
    for (int j2 = 0; j2 < 5; ++j2)
#pragma unroll
      for (int reg = 0; reg < 4; ++reg) {
        int r = 32 * wid + 16 * i2 + 4 * hi + reg;
        int c = 16 * j2 + lo;
        P[(size_t)r * 80 + c] = f2b(accn[i2][j2][reg]);
      }
}

// ---------- merge slices: x = num/(den+1e-9), elu, bf16 store ----------
__global__ void k_fin2(const unsigned short* __restrict__ parts, int nsl,
                       unsigned short* __restrict__ hb, int ldh) {
  int idx = blockIdx.x * 256 + threadIdx.x;
  int d = idx & 63, r = (idx >> 6) & 4095, h = idx >> 18;
  size_t b0 = ((size_t)(h * 32 + (r >> 7)) * nsl) * 10240 + (size_t)(r & 127) * 80;
  float nm = 0.f, dn = 0.f;
  for (int sl = 0; sl < nsl; ++sl) {
    const unsigned short* p = parts + b0 + (size_t)sl * 10240;
    nm += b2f(p[d]); dn += b2f(p[64]);
  }
  float x = nm / (dn + 1e-9f);
  x = x > 0.f ? x : expm1f(x);
  hb[(size_t)r * ldh + h * 64 + d] = f2b(x);
}

// ---------- layer-2 finalize + classifier ----------
__global__ __launch_bounds__(256) void k_fincls(const unsigned short* __restrict__ parts,
                                                int nsl, const float* __restrict__ Wc,
                                                const float* __restrict__ bc,
                                                float* __restrict__ out) {
  int r = blockIdx.x * 4 + (threadIdx.x >> 6);
  int d = threadIdx.x & 63;
  size_t b0 = ((size_t)(r >> 7) * nsl) * 10240 + (size_t)(r & 127) * 80;
  float nm = 0.f, dn = 0.f;
  for (int sl = 0; sl < nsl; ++sl) {
    const unsigned short* p = parts + b0 + (size_t)sl * 10240;
    nm += b2f(p[d]); dn += b2f(p[64]);
  }
  float x = nm / (dn + 1e-9f);
  x = x > 0.f ? x : expm1f(x);
#pragma unroll
  for (int cl = 0; cl < 10; ++cl) {
    float v = x * Wc[cl * 64 + d];
#pragma unroll
    for (int off = 32; off; off >>= 1) v += __shfl_xor(v, off);
    if (d == 0) out[(size_t)r * 10 + cl] = v + bc[cl];
  }
}

extern "C" void kernel_launch(void* const* d_in, const int* in_sizes, int n_in,
                              void* d_out, int out_size, void* d_ws, size_t ws_size,
                              hipStream_t stream) {
  (void)in_sizes; (void)n_in; (void)out_size; (void)ws_size;
  const float* feats    = (const float*)d_in[0];
  const float* counting = (const float*)d_in[1];
  const float* Wq1 = (const float*)d_in[2];
  const float* Wk1 = (const float*)d_in[3];
  const float* Wv1 = (const float*)d_in[4];
  const float* Wq2 = (const float*)d_in[5];
  const float* Wk2 = (const float*)d_in[6];
  const float* Wv2 = (const float*)d_in[7];
  const float* Wc  = (const float*)d_in[8];
  const float* bc  = (const float*)d_in[9];
  float* out = (float*)d_out;

  char* w = (char*)d_ws;
  size_t off = 0;
  auto alloc = [&](size_t bytes) { void* p = w + off; off += (bytes + 255) & ~(size_t)255; return p; };
  unsigned short* hnb    = (unsigned short*)alloc((size_t)4096 * 512 * 2);
  unsigned short* Q1b    = (unsigned short*)alloc((size_t)4096 * 256 * 2);
  unsigned short* K1b    = (unsigned short*)alloc((size_t)4096 * 256 * 2);
  unsigned short* V1xT   = (unsigned short*)alloc((size_t)272 * 4096 * 2);
  unsigned short* CVX1Tb = (unsigned short*)alloc((size_t)272 * 4096 * 2);
  unsigned short* h1b    = (unsigned short*)alloc((size_t)4096 * 256 * 2);
  unsigned short* Q2b    = (unsigned short*)alloc((size_t)4096 * 64 * 2);
  unsigned short* K2b    = (unsigned short*)alloc((size_t)4096 * 64 * 2);
  unsigned short* V2xT   = (unsigned short*)alloc((size_t)80 * 4096 * 2);
  unsigned short* CVX2Tb = (unsigned short*)alloc((size_t)68 * 4096 * 2);
  unsigned short* cntB   = (unsigned short*)alloc((size_t)4096 * 4096 * 2);
  unsigned short* big    = (unsigned short*)alloc((size_t)36 * 1024 * 1024);

  k_norm<<<1024, 256, 0, stream>>>(feats, hnb);
  k_cvtcnt<<<2048, 256, 0, stream>>>(counting, cntB);

  // layer-1 Q/K/V (Q prescaled by 0.125*log2e; V transposed + ones rows)
  k_projqkv<<<dim3(32, 6), 256, 0, stream>>>(hnb, 512, Wq1, Wk1, Wv1, 256, 2,
                                             Q1b, K1b, V1xT, 4, QSCALE);
  // CVX1 = counting @ [V1|1]
  k_cvxg<17, 3><<<dim3(32, 16), 256, 0, stream>>>(cntB, V1xT, big);
  k_tredB<<<dim3(64, 5), 256, 0, stream>>>(big, 272, 16, CVX1Tb, 272);
  // layer-1 fused attention + merge
  k_attn<<<dim3(32, 4, 4), 256, 0, stream>>>(Q1b, K1b, 256, CVX1Tb, big);
  k_fin2<<<4096, 256, 0, stream>>>(big, 4, h1b, 256);

  // layer-2 Q/K/V
  k_projqkv<<<dim3(32, 3), 256, 0, stream>>>(h1b, 256, Wq2, Wk2, Wv2, 64, 1,
                                             Q2b, K2b, V2xT, 16, QSCALE);
  // CVX2
  k_cvxg<5, 4><<<dim3(32, 16), 256, 0, stream>>>(cntB, V2xT, big);
  k_tredB<<<dim3(64, 2), 256, 0, stream>>>(big, 80, 16, CVX2Tb, 68);
  // layer-2 fused attention + finalize + classifier
  k_attn<<<dim3(32, 1, 16), 256, 0, stream>>>(Q2b, K2b, 64, CVX2Tb, big);
  k_fincls<<<1024, 256, 0, stream>>>(big, 16, Wc, bc, out);
}

// Round 11
// 173.789 us; speedup vs baseline: 1.0075x; 1.0075x over previous
//
#include <hip/hip_runtime.h>
#include <hip/hip_bf16.h>
#include <math.h>

#define NN4   4096
#define QSCALE 0.180336880111120420f   // 0.125 * log2(e); exp(S/8)=exp2(S*QSCALE)

typedef __attribute__((ext_vector_type(8))) short short8;
typedef __attribute__((ext_vector_type(8))) unsigned short ushort8;
typedef __attribute__((ext_vector_type(4))) unsigned short ushort4v;
typedef __attribute__((ext_vector_type(4))) float f32x4;

__device__ __forceinline__ unsigned short f2b(float f) {
  union { __hip_bfloat16 h; unsigned short u; } v;
  v.h = __float2bfloat16(f);
  return v.u;
}
__device__ __forceinline__ float b2f(unsigned short s) {
  return __uint_as_float(((unsigned int)s) << 16);
}
__device__ __forceinline__ ushort8 cvt8(f32x4 a, f32x4 b) {
  return (ushort8){f2b(a[0]), f2b(a[1]), f2b(a[2]), f2b(a[3]),
                   f2b(b[0]), f2b(b[1]), f2b(b[2]), f2b(b[3])};
}

#define GLOAD16(gp, lp) __builtin_amdgcn_global_load_lds( \
    (const __attribute__((address_space(1))) void*)(gp),  \
    (__attribute__((address_space(3))) void*)(lp), 16, 0, 0)

// ---------------- row normalize (mean/std over 512, ddof=1) -> bf16 ----------------
__global__ __launch_bounds__(256) void k_norm(const float* __restrict__ x,
                                              unsigned short* __restrict__ y) {
  int row  = blockIdx.x * 4 + (threadIdx.x >> 6);
  int lane = threadIdx.x & 63;
  const float4* src = (const float4*)(x + (size_t)row * 512);
  float4 a = src[lane];
  float4 b = src[lane + 64];
  float s = a.x + a.y + a.z + a.w + b.x + b.y + b.z + b.w;
#pragma unroll
  for (int off = 32; off; off >>= 1) s += __shfl_xor(s, off);
  float mean = s * (1.0f / 512.0f);
  float ssq = 0.f, d;
  d = a.x - mean; ssq += d * d;  d = a.y - mean; ssq += d * d;
  d = a.z - mean; ssq += d * d;  d = a.w - mean; ssq += d * d;
  d = b.x - mean; ssq += d * d;  d = b.y - mean; ssq += d * d;
  d = b.z - mean; ssq += d * d;  d = b.w - mean; ssq += d * d;
#pragma unroll
  for (int off = 32; off; off >>= 1) ssq += __shfl_xor(ssq, off);
  float inv = 1.0f / (sqrtf(ssq * (1.0f / 511.0f)) + 1e-9f);
  unsigned short* dst = y + (size_t)row * 512;
  ushort4v va = (ushort4v){f2b((a.x - mean) * inv), f2b((a.y - mean) * inv),
                           f2b((a.z - mean) * inv), f2b((a.w - mean) * inv)};
  ushort4v vb = (ushort4v){f2b((b.x - mean) * inv), f2b((b.y - mean) * inv),
                           f2b((b.z - mean) * inv), f2b((b.w - mean) * inv)};
  *(ushort4v*)(dst + lane * 4)       = va;
  *(ushort4v*)(dst + 256 + lane * 4) = vb;
}

// ---------------- counting f32 -> bf16 copy (one-time) ----------------
__global__ __launch_bounds__(256) void k_cvtcnt(const float* __restrict__ in,
                                                unsigned short* __restrict__ out) {
  size_t i = ((size_t)blockIdx.x * 256 + threadIdx.x) * 8;
  const size_t stride = (size_t)gridDim.x * 256 * 8;
  for (; i < (size_t)4096 * 4096; i += stride) {
    f32x4 a = *(const f32x4*)(in + i);
    f32x4 b = *(const f32x4*)(in + i + 4);
    *(ushort8*)(out + i) = cvt8(a, b);
  }
}

// ----------- fused Q/K/V projection: C = A[4096,K] @ W[N,K]^T -----------
__global__ __launch_bounds__(256) void k_projqkv(
    const unsigned short* __restrict__ Ap, int K,
    const float* __restrict__ Wq, const float* __restrict__ Wk,
    const float* __restrict__ Wv, int N, int nT,
    unsigned short* __restrict__ Qo, unsigned short* __restrict__ Ko,
    unsigned short* __restrict__ VT, int padrows, float qscale) {
  __shared__ unsigned short As[128 * 40];
  __shared__ unsigned short Bs[128 * 40];
  const int tid = threadIdx.x;
  const int sel = blockIdx.y / nT;
  const int n0 = (blockIdx.y % nT) * 128;
  const int m0 = blockIdx.x * 128;
  const float* Bp = sel == 0 ? Wq : (sel == 1 ? Wk : Wv);
  const float bscale = sel == 0 ? qscale : 1.0f;
  const int lane = tid & 63, wid = tid >> 6;
  const int hi = lane >> 4, lo = lane & 15;
  const int wr = (wid >> 1) << 6, wc = (wid & 1) << 6;
  const int srow = tid >> 1, sk = (tid & 1) << 4;
  f32x4 acc[4][4];
#pragma unroll
  for (int i = 0; i < 4; ++i)
#pragma unroll
    for (int j = 0; j < 4; ++j) acc[i][j] = (f32x4){0.f, 0.f, 0.f, 0.f};

  for (int k0 = 0; k0 < K; k0 += 32) {
    ushort8 va0, va1, vb0, vb1;
    {
      const unsigned short* s = Ap + (size_t)(m0 + srow) * K + k0 + sk;
      va0 = *(const ushort8*)(s);
      va1 = *(const ushort8*)(s + 8);
    }
    {
      int gr = n0 + srow;
      if (gr < N) {
        const float* s = Bp + (size_t)gr * K + k0 + sk;
        f32x4 f0 = *(const f32x4*)(s) * bscale;
        f32x4 f1 = *(const f32x4*)(s + 4) * bscale;
        f32x4 f2 = *(const f32x4*)(s + 8) * bscale;
        f32x4 f3 = *(const f32x4*)(s + 12) * bscale;
        vb0 = cvt8(f0, f1); vb1 = cvt8(f2, f3);
      } else { vb0 = (ushort8)0; vb1 = (ushort8)0; }
    }
    __syncthreads();
    *(ushort8*)&As[srow * 40 + sk]     = va0;
    *(ushort8*)&As[srow * 40 + sk + 8] = va1;
    *(ushort8*)&Bs[srow * 40 + sk]     = vb0;
    *(ushort8*)&Bs[srow * 40 + sk + 8] = vb1;
    __syncthreads();
    short8 af[4], bf[4];
#pragma unroll
    for (int i = 0; i < 4; ++i)
      af[i] = *(const short8*)&As[(wr + (i << 4) + lo) * 40 + hi * 8];
#pragma unroll
    for (int j = 0; j < 4; ++j)
      bf[j] = *(const short8*)&Bs[(wc + (j << 4) + lo) * 40 + hi * 8];
#pragma unroll
    for (int i = 0; i < 4; ++i)
#pragma unroll
      for (int j = 0; j < 4; ++j)
        acc[i][j] = __builtin_amdgcn_mfma_f32_16x16x32_bf16(af[i], bf[j], acc[i][j], 0, 0, 0);
  }

  if (sel < 2) {
    unsigned short* Cp = sel == 0 ? Qo : Ko;
#pragma unroll
    for (int i = 0; i < 4; ++i)
#pragma unroll
      for (int j = 0; j < 4; ++j)
#pragma unroll
        for (int reg = 0; reg < 4; ++reg) {
          int r = m0 + wr + (i << 4) + (hi << 2) + reg;
          int c = n0 + wc + (j << 4) + lo;
          if (c < N) Cp[(size_t)r * N + c] = f2b(acc[i][j][reg]);
        }
  } else {
#pragma unroll
    for (int i = 0; i < 4; ++i)
#pragma unroll
      for (int j = 0; j < 4; ++j) {
        int c = n0 + wc + (j << 4) + lo;
        if (c < N) {
          int hh = c >> 6, dd = c & 63;
          int rb = m0 + wr + (i << 4) + (hi << 2);
          ushort4v pk = (ushort4v){f2b(acc[i][j][0]), f2b(acc[i][j][1]),
                                   f2b(acc[i][j][2]), f2b(acc[i][j][3])};
          *(ushort4v*)&VT[(size_t)(hh * 68 + dd) * NN4 + rb] = pk;
        }
      }
    int hstart = n0 >> 6;
    int hcnt = (N - n0) >> 6; if (hcnt > 2) hcnt = 2;
    int tot = hcnt * padrows * 128;
    for (int e = tid; e < tot; e += 256) {
      int hh = hstart + e / (padrows * 128);
      int rem = e % (padrows * 128);
      int j = rem >> 7, col = m0 + (rem & 127);
      VT[(size_t)(hh * 68 + 64 + j) * NN4 + col] = (j == 0) ? 0x3F80 : 0;
    }
  }
}

// --------- CVX split-K (T3+T4): Pb[z][4096][NF*16] = cntB-slice @ Bt^T ---------
// 3-buffer, 2-deep prefetch, counted vmcnt, raw s_barrier (no implicit drain).
template<int NF, int MINW>
__global__ __launch_bounds__(256, MINW) void k_cvxg(
    const unsigned short* __restrict__ cntB,
    const unsigned short* __restrict__ Bt,     // [NF*16][4096] bf16
    unsigned short* __restrict__ Pb) {
  constexpr int LDB = NF * 16;
  __shared__ unsigned short As[3][4096];       // 128 rows x 32 k (swizzled slots)
  __shared__ unsigned short Bs[3][NF * 512];
  const int tid = threadIdx.x, lane = tid & 63, wid = tid >> 6;
  const int hi = lane >> 4, lo = lane & 15;
  const int m0 = blockIdx.x * 128;
  const int kbeg = blockIdx.y << 8;
  const int boff = (lo * 64 + hi * 16) ^ (((lo >> 1) & 3) << 4);   // B read (bytes)

  f32x4 acc[2][NF];
#pragma unroll
  for (int i = 0; i < 2; ++i)
#pragma unroll
    for (int j = 0; j < NF; ++j) acc[i][j] = (f32x4){0.f, 0.f, 0.f, 0.f};

  auto STAGE = [&](int t, int buf) {
    const int k0 = kbeg + t * 32;
#pragma unroll
    for (int s = 0; s < 2; ++s) {
      int ch = s * 4 + wid;
      int row = ch * 16 + (lane >> 2);
      int hia = (lane & 3) ^ ((row >> 1) & 3);
      GLOAD16(cntB + (size_t)(m0 + row) * 4096 + k0 + hia * 8,
              (char*)&As[buf][0] + ch * 1024);
    }
    for (int c = wid; c < NF; c += 4) {
      int P = c * 1024 + lane * 16;
      int L = P ^ ((P >> 3) & 0x30);
      GLOAD16(Bt + (size_t)(L >> 6) * 4096 + k0 + ((L & 63) >> 1),
              (char*)&Bs[buf][0] + c * 1024);
    }
  };

  const int r0 = 32 * wid + lo, r1 = r0 + 16;
  const int ho = ((hi ^ ((r0 >> 1) & 3)) << 3);

  auto COMPUTE = [&](int buf) {
    short8 af0 = *(const short8*)&As[buf][r0 * 32 + ho];
    short8 af1 = *(const short8*)&As[buf][r1 * 32 + ho];
    __builtin_amdgcn_s_setprio(1);
#pragma unroll
    for (int j = 0; j < NF; ++j) {
      short8 bf = *(const short8*)((const char*)&Bs[buf][0] + j * 1024 + boff);
      acc[0][j] = __builtin_amdgcn_mfma_f32_16x16x32_bf16(af0, bf, acc[0][j], 0, 0, 0);
      acc[1][j] = __builtin_amdgcn_mfma_f32_16x16x32_bf16(af1, bf, acc[1][j], 0, 0, 0);
    }
    __builtin_amdgcn_s_setprio(0);
  };

  // per-wave loads per stage: A=2, B=NF/4 (+1 for wid < NF%4)
  const bool extra = wid < (NF & 3);

  STAGE(0, 0);
  STAGE(1, 1);

  for (int t = 0; t < 7; ++t) {
    // wait: stage t complete; stage t+1's loads may remain in flight
    if constexpr (NF == 17) {
      if (extra) asm volatile("s_waitcnt vmcnt(7)" ::: "memory");
      else       asm volatile("s_waitcnt vmcnt(6)" ::: "memory");
    } else {
      if (extra) asm volatile("s_waitcnt vmcnt(4)" ::: "memory");
      else       asm volatile("s_waitcnt vmcnt(3)" ::: "memory");
    }
    __builtin_amdgcn_s_barrier();
    if (t + 2 < 8) STAGE(t + 2, (t + 2) % 3);     // overwrites buf of t-1
    COMPUTE(t % 3);
  }
  asm volatile("s_waitcnt vmcnt(0)" ::: "memory"); // last stage: nothing younger in flight
  __builtin_amdgcn_s_barrier();
  COMPUTE(7 % 3);

  unsigned short* P = Pb + (size_t)blockIdx.y * 4096 * LDB;
#pragma unroll
  for (int i = 0; i < 2; ++i)
#pragma unroll
    for (int j = 0; j < NF; ++j)
#pragma unroll
      for (int reg = 0; reg < 4; ++reg) {
        int r = m0 + 32 * wid + 16 * i + 4 * hi + reg;
        P[(size_t)r * LDB + 16 * j + lo] = f2b(acc[i][j][reg]);
      }
}

// ---------- reduce bf16 split-K partials + transpose -> bf16 [orow][4096] ----------
__global__ __launch_bounds__(256) void k_tredB(const unsigned short* __restrict__ in, int ld,
                                               int nsl, unsigned short* __restrict__ out,
                                               int orow) {
  __shared__ float t[64][65];
  const int n0 = blockIdx.x << 6, d0 = blockIdx.y << 6;
  const int o  = threadIdx.x & 7;
  const int rr = threadIdx.x >> 3;
  const size_t pstride = (size_t)4096 * ld;
  const bool valid = (o * 8) < (ld - d0);
#pragma unroll
  for (int pass = 0; pass < 2; ++pass) {
    const int r = rr + (pass << 5);
    float a[8] = {0.f, 0.f, 0.f, 0.f, 0.f, 0.f, 0.f, 0.f};
    if (valid) {
      const unsigned short* p = in + (size_t)(n0 + r) * ld + d0 + o * 8;
      for (int z = 0; z < nsl; ++z) {
        ushort8 v = *(const ushort8*)(p + (size_t)z * pstride);
#pragma unroll
        for (int k = 0; k < 8; ++k) a[k] += b2f(v[k]);
      }
    }
#pragma unroll
    for (int k = 0; k < 8; ++k) t[o * 8 + k][r] = a[k];
  }
  __syncthreads();
  const int c = threadIdx.x & 63, r4 = threadIdx.x >> 6;
#pragma unroll
  for (int i = 0; i < 16; ++i) {
    int dr = r4 + (i << 2);
    if (d0 + dr < orow)
      out[(size_t)(d0 + dr) * 4096 + n0 + c] = f2b(t[dr][c]);
  }
}

// ---------------- fused GKAT attention: num = exp2(Q K^T) @ CVX^T ----------------
__global__ __launch_bounds__(256, 2) void k_attn(
    const unsigned short* __restrict__ Qg, const unsigned short* __restrict__ Kg,
    int ldqk, const unsigned short* __restrict__ CVg,
    unsigned short* __restrict__ Pb) {
  __shared__ unsigned short Ks[128 * 72];
  __shared__ unsigned short Cs[80 * 136];
  __shared__ unsigned short Es[128 * 136];     // byte ^= (row&7)<<5 swizzle
  const int tid = threadIdx.x, lane = tid & 63, wid = tid >> 6;
  const int hi = lane >> 4, lo = lane & 15;
  const int qb = blockIdx.x, h = blockIdx.y, sl = blockIdx.z;
  const int n0 = qb * 128;
  const int MS = 4096 / gridDim.z;
  const int m0beg = sl * MS;
  const int wr = (wid >> 1) << 6, wc = (wid & 1) << 6;

  short8 qf[4][2];
  const unsigned short* Qh = Qg + (size_t)h * 64;
#pragma unroll
  for (int j = 0; j < 4; ++j)
#pragma unroll
    for (int t = 0; t < 2; ++t)
      qf[j][t] = *(const short8*)(Qh + (size_t)(n0 + wc + 16 * j + lo) * ldqk + t * 32 + hi * 8);

  const unsigned short* CVh = CVg + (size_t)h * 68 * NN4;
  const unsigned short* Kh  = Kg + (size_t)h * 64;

  const int krow = tid >> 1, khalf = (tid & 1) << 5;
  int crdR[5], crdW[5], ccol[5];
#pragma unroll
  for (int k = 0; k < 5; ++k) {
    int c = tid + k * 256;
    int row = c >> 4;
    crdW[k] = row;
    crdR[k] = row < 68 ? row : 67;
    ccol[k] = (c & 15) << 3;
  }
  ushort8 krg[4], crg[5];

  auto LOADK = [&](int m0) {
    const unsigned short* src = Kh + (size_t)(m0 + krow) * ldqk + khalf;
    krg[0] = *(const ushort8*)(src);
    krg[1] = *(const ushort8*)(src + 8);
    krg[2] = *(const ushort8*)(src + 16);
    krg[3] = *(const ushort8*)(src + 24);
  };
  auto LOADC = [&](int m0) {
#pragma unroll
    for (int k = 0; k < 5; ++k)
      crg[k] = *(const ushort8*)(CVh + (size_t)crdR[k] * NN4 + m0 + ccol[k]);
  };
  auto WRITEK = [&]() {
    unsigned short* dp = &Ks[krow * 72 + khalf];
    *(ushort8*)(dp) = krg[0];      *(ushort8*)(dp + 8) = krg[1];
    *(ushort8*)(dp + 16) = krg[2]; *(ushort8*)(dp + 24) = krg[3];
  };
  auto WRITEC = [&]() {
#pragma unroll
    for (int k = 0; k < 5; ++k)
      *(ushort8*)&Cs[crdW[k] * 136 + ccol[k]] = crg[k];
  };

  f32x4 accn[2][5];
#pragma unroll
  for (int i = 0; i < 2; ++i)
#pragma unroll
    for (int j = 0; j < 5; ++j) accn[i][j] = (f32x4){0.f, 0.f, 0.f, 0.f};

  LOADK(m0beg); LOADC(m0beg);
  WRITEK(); WRITEC();
  __syncthreads();

  for (int mt = 0; mt < MS; mt += 128) {
    const int m0 = m0beg + mt;
    const bool more = (mt + 128) < MS;
    if (more) { LOADK(m0 + 128); LOADC(m0 + 128); }
    short8 kf[4][2];
#pragma unroll
    for (int i = 0; i < 4; ++i)
#pragma unroll
      for (int t = 0; t < 2; ++t)
        kf[i][t] = *(const short8*)&Ks[(wr + 16 * i + lo) * 72 + t * 32 + hi * 8];
    f32x4 s[4][4];
#pragma unroll
    for (int i = 0; i < 4; ++i)
#pragma unroll
      for (int j = 0; j < 4; ++j) s[i][j] = (f32x4){0.f, 0.f, 0.f, 0.f};
    __builtin_amdgcn_s_setprio(1);
#pragma unroll
    for (int t = 0; t < 2; ++t)
#pragma unroll
      for (int i = 0; i < 4; ++i)
#pragma unroll
        for (int j = 0; j < 4; ++j)
          s[i][j] = __builtin_amdgcn_mfma_f32_16x16x32_bf16(kf[i][t], qf[j][t], s[i][j], 0, 0, 0);
    __builtin_amdgcn_s_setprio(0);
#pragma unroll
    for (int i = 0; i < 4; ++i)
#pragma unroll
      for (int j = 0; j < 4; ++j) {
        unsigned int u0 = (unsigned int)f2b(__builtin_amdgcn_exp2f(s[i][j][0])) |
                          ((unsigned int)f2b(__builtin_amdgcn_exp2f(s[i][j][1])) << 16);
        unsigned int u1 = (unsigned int)f2b(__builtin_amdgcn_exp2f(s[i][j][2])) |
                          ((unsigned int)f2b(__builtin_amdgcn_exp2f(s[i][j][3])) << 16);
        unsigned long long pk = (unsigned long long)u0 | ((unsigned long long)u1 << 32);
        int row = wc + 16 * j + lo;
        int byte = row * 272 + (wr + 16 * i + 4 * hi) * 2;
        *(unsigned long long*)((char*)Es + (byte ^ ((row & 7) << 5))) = pk;
      }
    __syncthreads();
    if (more) WRITEK();
    __builtin_amdgcn_s_setprio(1);
#pragma unroll
    for (int t2 = 0; t2 < 4; ++t2) {
      int r0 = 32 * wid + lo, r1 = r0 + 16;
      int cb = (t2 * 32 + hi * 8) * 2;
      short8 ea0 = *(const short8*)((const char*)Es + ((r0 * 272 + cb) ^ ((r0 & 7) << 5)));
      short8 ea1 = *(const short8*)((const char*)Es + ((r1 * 272 + cb) ^ ((r1 & 7) << 5)));
      short8 cbv[5];
#pragma unroll
      for (int j2 = 0; j2 < 5; ++j2)
        cbv[j2] = *(const short8*)&Cs[(16 * j2 + lo) * 136 + t2 * 32 + hi * 8];
#pragma unroll
      for (int j2 = 0; j2 < 5; ++j2) {
        accn[0][j2] = __builtin_amdgcn_mfma_f32_16x16x32_bf16(ea0, cbv[j2], accn[0][j2], 0, 0, 0);
        accn[1][j2] = __builtin_amdgcn_mfma_f32_16x16x32_bf16(ea1, cbv[j2], accn[1][j2], 0, 0, 0);
      }
    }
    __builtin_amdgcn_s_setprio(0);
    __syncthreads();
    if (more) { WRITEC(); __syncthreads(); }
  }
  unsigned short* P = Pb + (((size_t)h * gridDim.x + qb) * gridDim.z + sl) * (128 * 80);
#pragma unroll
  for (int i2 = 0; i2 < 2; ++i2)
#pragma unroll
    for (int j2 = 0; j2 < 5; ++j2)
#pragma unroll
      for (int reg = 0; reg < 4; ++reg) {
        int r = 32 * wid + 16 * i2 + 4 * hi + reg;
        int c = 16 * j2 + lo;
        P[(size_t)r * 80 + c] = f2b(accn[i2][j2][reg]);
      }
}

// ---------- merge slices: x = num/(den+1e-9), elu, bf16 store ----------
__global__ void k_fin2(const unsigned short* __restrict__ parts, int nsl,
                       unsigned short* __restrict__ hb, int ldh) {
  int idx = blockIdx.x * 256 + threadIdx.x;
  int d = idx & 63, r = (idx >> 6) & 4095, h = idx >> 18;
  size_t b0 = ((size_t)(h * 32 + (r >> 7)) * nsl) * 10240 + (size_t)(r & 127) * 80;
  float nm = 0.f, dn = 0.f;
  for (int sl = 0; sl < nsl; ++sl) {
    const unsigned short* p = parts + b0 + (size_t)sl * 10240;
    nm += b2f(p[d]); dn += b2f(p[64]);
  }
  float x = nm / (dn + 1e-9f);
  x = x > 0.f ? x : expm1f(x);
  hb[(size_t)r * ldh + h * 64 + d] = f2b(x);
}

// ---------- layer-2 finalize + classifier ----------
__global__ __launch_bounds__(256) void k_fincls(const unsigned short* __restrict__ parts,
                                                int nsl, const float* __restrict__ Wc,
                                                const float* __restrict__ bc,
                                                float* __restrict__ out) {
  int r = blockIdx.x * 4 + (threadIdx.x >> 6);
  int d = threadIdx.x & 63;
  size_t b0 = ((size_t)(r >> 7) * nsl) * 10240 + (size_t)(r & 127) * 80;
  float nm = 0.f, dn = 0.f;
  for (int sl = 0; sl < nsl; ++sl) {
    const unsigned short* p = parts + b0 + (size_t)sl * 10240;
    nm += b2f(p[d]); dn += b2f(p[64]);
  }
  float x = nm / (dn + 1e-9f);
  x = x > 0.f ? x : expm1f(x);
#pragma unroll
  for (int cl = 0; cl < 10; ++cl) {
    float v = x * Wc[cl * 64 + d];
#pragma unroll
    for (int off = 32; off; off >>= 1) v += __shfl_xor(v, off);
    if (d == 0) out[(size_t)r * 10 + cl] = v + bc[cl];
  }
}

extern "C" void kernel_launch(void* const* d_in, const int* in_sizes, int n_in,
                              void* d_out, int out_size, void* d_ws, size_t ws_size,
                              hipStream_t stream) {
  (void)in_sizes; (void)n_in; (void)out_size; (void)ws_size;
  const float* feats    = (const float*)d_in[0];
  const float* counting = (const float*)d_in[1];
  const float* Wq1 = (const float*)d_in[2];
  const float* Wk1 = (const float*)d_in[3];
  const float* Wv1 = (const float*)d_in[4];
  const float* Wq2 = (const float*)d_in[5];
  const float* Wk2 = (const float*)d_in[6];
  const float* Wv2 = (const float*)d_in[7];
  const float* Wc  = (const float*)d_in[8];
  const float* bc  = (const float*)d_in[9];
  float* out = (float*)d_out;

  char* w = (char*)d_ws;
  size_t off = 0;
  auto alloc = [&](size_t bytes) { void* p = w + off; off += (bytes + 255) & ~(size_t)255; return p; };
  unsigned short* hnb    = (unsigned short*)alloc((size_t)4096 * 512 * 2);
  unsigned short* Q1b    = (unsigned short*)alloc((size_t)4096 * 256 * 2);
  unsigned short* K1b    = (unsigned short*)alloc((size_t)4096 * 256 * 2);
  unsigned short* V1xT   = (unsigned short*)alloc((size_t)272 * 4096 * 2);
  unsigned short* CVX1Tb = (unsigned short*)alloc((size_t)272 * 4096 * 2);
  unsigned short* h1b    = (unsigned short*)alloc((size_t)4096 * 256 * 2);
  unsigned short* Q2b    = (unsigned short*)alloc((size_t)4096 * 64 * 2);
  unsigned short* K2b    = (unsigned short*)alloc((size_t)4096 * 64 * 2);
  unsigned short* V2xT   = (unsigned short*)alloc((size_t)80 * 4096 * 2);
  unsigned short* CVX2Tb = (unsigned short*)alloc((size_t)68 * 4096 * 2);
  unsigned short* cntB   = (unsigned short*)alloc((size_t)4096 * 4096 * 2);
  unsigned short* big    = (unsigned short*)alloc((size_t)36 * 1024 * 1024);

  k_norm<<<1024, 256, 0, stream>>>(feats, hnb);
  k_cvtcnt<<<2048, 256, 0, stream>>>(counting, cntB);

  // layer-1 Q/K/V (Q prescaled by 0.125*log2e; V transposed + ones rows)
  k_projqkv<<<dim3(32, 6), 256, 0, stream>>>(hnb, 512, Wq1, Wk1, Wv1, 256, 2,
                                             Q1b, K1b, V1xT, 4, QSCALE);
  // CVX1 = counting @ [V1|1]
  k_cvxg<17, 2><<<dim3(32, 16), 256, 0, stream>>>(cntB, V1xT, big);
  k_tredB<<<dim3(64, 5), 256, 0, stream>>>(big, 272, 16, CVX1Tb, 272);
  // layer-1 fused attention + merge
  k_attn<<<dim3(32, 4, 4), 256, 0, stream>>>(Q1b, K1b, 256, CVX1Tb, big);
  k_fin2<<<4096, 256, 0, stream>>>(big, 4, h1b, 256);

  // layer-2 Q/K/V
  k_projqkv<<<dim3(32, 3), 256, 0, stream>>>(h1b, 256, Wq2, Wk2, Wv2, 64, 1,
                                             Q2b, K2b, V2xT, 16, QSCALE);
  // CVX2
  k_cvxg<5, 4><<<dim3(32, 16), 256, 0, stream>>>(cntB, V2xT, big);
  k_tredB<<<dim3(64, 2), 256, 0, stream>>>(big, 80, 16, CVX2Tb, 68);
  // layer-2 fused attention + finalize + classifier
  k_attn<<<dim3(32, 1, 16), 256, 0, stream>>>(Q2b, K2b, 64, CVX2Tb, big);
  k_fincls<<<1024, 256, 0, stream>>>(big, 16, Wc, bc, out);
}

// Round 12
// 162.485 us; speedup vs baseline: 1.0776x; 1.0696x over previous
//
#include <hip/hip_runtime.h>
#include <hip/hip_bf16.h>
#include <math.h>

#define NN4   4096
#define QSCALE 0.180336880111120420f   // 0.125 * log2(e); exp(S/8)=exp2(S*QSCALE)

typedef __attribute__((ext_vector_type(8))) short short8;
typedef __attribute__((ext_vector_type(8))) unsigned short ushort8;
typedef __attribute__((ext_vector_type(4))) unsigned short ushort4v;
typedef __attribute__((ext_vector_type(4))) float f32x4;

__device__ __forceinline__ unsigned short f2b(float f) {
  union { __hip_bfloat16 h; unsigned short u; } v;
  v.h = __float2bfloat16(f);
  return v.u;
}
__device__ __forceinline__ float b2f(unsigned short s) {
  return __uint_as_float(((unsigned int)s) << 16);
}
__device__ __forceinline__ ushort8 cvt8(f32x4 a, f32x4 b) {
  return (ushort8){f2b(a[0]), f2b(a[1]), f2b(a[2]), f2b(a[3]),
                   f2b(b[0]), f2b(b[1]), f2b(b[2]), f2b(b[3])};
}

#define GLOAD16(gp, lp) __builtin_amdgcn_global_load_lds( \
    (const __attribute__((address_space(1))) void*)(gp),  \
    (__attribute__((address_space(3))) void*)(lp), 16, 0, 0)

// ---------------- row normalize (mean/std over 512, ddof=1) -> bf16 ----------------
__global__ __launch_bounds__(256) void k_norm(const float* __restrict__ x,
                                              unsigned short* __restrict__ y) {
  int row  = blockIdx.x * 4 + (threadIdx.x >> 6);
  int lane = threadIdx.x & 63;
  const float4* src = (const float4*)(x + (size_t)row * 512);
  float4 a = src[lane];
  float4 b = src[lane + 64];
  float s = a.x + a.y + a.z + a.w + b.x + b.y + b.z + b.w;
#pragma unroll
  for (int off = 32; off; off >>= 1) s += __shfl_xor(s, off);
  float mean = s * (1.0f / 512.0f);
  float ssq = 0.f, d;
  d = a.x - mean; ssq += d * d;  d = a.y - mean; ssq += d * d;
  d = a.z - mean; ssq += d * d;  d = a.w - mean; ssq += d * d;
  d = b.x - mean; ssq += d * d;  d = b.y - mean; ssq += d * d;
  d = b.z - mean; ssq += d * d;  d = b.w - mean; ssq += d * d;
#pragma unroll
  for (int off = 32; off; off >>= 1) ssq += __shfl_xor(ssq, off);
  float inv = 1.0f / (sqrtf(ssq * (1.0f / 511.0f)) + 1e-9f);
  unsigned short* dst = y + (size_t)row * 512;
  ushort4v va = (ushort4v){f2b((a.x - mean) * inv), f2b((a.y - mean) * inv),
                           f2b((a.z - mean) * inv), f2b((a.w - mean) * inv)};
  ushort4v vb = (ushort4v){f2b((b.x - mean) * inv), f2b((b.y - mean) * inv),
                           f2b((b.z - mean) * inv), f2b((b.w - mean) * inv)};
  *(ushort4v*)(dst + lane * 4)       = va;
  *(ushort4v*)(dst + 256 + lane * 4) = vb;
}

// ----------- fused Q/K/V projection: C = A[4096,K] @ W[N,K]^T -----------
// grid (32, 3*nT): sel = y/nT (0=Q,1=K,2=V). Q staged with qscale (folds
// 0.125*log2e). V written TRANSPOSED to VT[(h*68+d)][4096] + ones/pad rows.
__global__ __launch_bounds__(256) void k_projqkv(
    const unsigned short* __restrict__ Ap, int K,
    const float* __restrict__ Wq, const float* __restrict__ Wk,
    const float* __restrict__ Wv, int N, int nT,
    unsigned short* __restrict__ Qo, unsigned short* __restrict__ Ko,
    unsigned short* __restrict__ VT, int padrows, float qscale) {
  __shared__ unsigned short As[128 * 40];
  __shared__ unsigned short Bs[128 * 40];
  const int tid = threadIdx.x;
  const int sel = blockIdx.y / nT;
  const int n0 = (blockIdx.y % nT) * 128;
  const int m0 = blockIdx.x * 128;
  const float* Bp = sel == 0 ? Wq : (sel == 1 ? Wk : Wv);
  const float bscale = sel == 0 ? qscale : 1.0f;
  const int lane = tid & 63, wid = tid >> 6;
  const int hi = lane >> 4, lo = lane & 15;
  const int wr = (wid >> 1) << 6, wc = (wid & 1) << 6;
  const int srow = tid >> 1, sk = (tid & 1) << 4;
  f32x4 acc[4][4];
#pragma unroll
  for (int i = 0; i < 4; ++i)
#pragma unroll
    for (int j = 0; j < 4; ++j) acc[i][j] = (f32x4){0.f, 0.f, 0.f, 0.f};

  for (int k0 = 0; k0 < K; k0 += 32) {
    ushort8 va0, va1, vb0, vb1;
    {
      const unsigned short* s = Ap + (size_t)(m0 + srow) * K + k0 + sk;
      va0 = *(const ushort8*)(s);
      va1 = *(const ushort8*)(s + 8);
    }
    {
      int gr = n0 + srow;
      if (gr < N) {
        const float* s = Bp + (size_t)gr * K + k0 + sk;
        f32x4 f0 = *(const f32x4*)(s) * bscale;
        f32x4 f1 = *(const f32x4*)(s + 4) * bscale;
        f32x4 f2 = *(const f32x4*)(s + 8) * bscale;
        f32x4 f3 = *(const f32x4*)(s + 12) * bscale;
        vb0 = cvt8(f0, f1); vb1 = cvt8(f2, f3);
      } else { vb0 = (ushort8)0; vb1 = (ushort8)0; }
    }
    __syncthreads();
    *(ushort8*)&As[srow * 40 + sk]     = va0;
    *(ushort8*)&As[srow * 40 + sk + 8] = va1;
    *(ushort8*)&Bs[srow * 40 + sk]     = vb0;
    *(ushort8*)&Bs[srow * 40 + sk + 8] = vb1;
    __syncthreads();
    short8 af[4], bf[4];
#pragma unroll
    for (int i = 0; i < 4; ++i)
      af[i] = *(const short8*)&As[(wr + (i << 4) + lo) * 40 + hi * 8];
#pragma unroll
    for (int j = 0; j < 4; ++j)
      bf[j] = *(const short8*)&Bs[(wc + (j << 4) + lo) * 40 + hi * 8];
#pragma unroll
    for (int i = 0; i < 4; ++i)
#pragma unroll
      for (int j = 0; j < 4; ++j)
        acc[i][j] = __builtin_amdgcn_mfma_f32_16x16x32_bf16(af[i], bf[j], acc[i][j], 0, 0, 0);
  }

  if (sel < 2) {
    unsigned short* Cp = sel == 0 ? Qo : Ko;
#pragma unroll
    for (int i = 0; i < 4; ++i)
#pragma unroll
      for (int j = 0; j < 4; ++j)
#pragma unroll
        for (int reg = 0; reg < 4; ++reg) {
          int r = m0 + wr + (i << 4) + (hi << 2) + reg;
          int c = n0 + wc + (j << 4) + lo;
          if (c < N) Cp[(size_t)r * N + c] = f2b(acc[i][j][reg]);
        }
  } else {
#pragma unroll
    for (int i = 0; i < 4; ++i)
#pragma unroll
      for (int j = 0; j < 4; ++j) {
        int c = n0 + wc + (j << 4) + lo;
        if (c < N) {
          int hh = c >> 6, dd = c & 63;
          int rb = m0 + wr + (i << 4) + (hi << 2);
          ushort4v pk = (ushort4v){f2b(acc[i][j][0]), f2b(acc[i][j][1]),
                                   f2b(acc[i][j][2]), f2b(acc[i][j][3])};
          *(ushort4v*)&VT[(size_t)(hh * 68 + dd) * NN4 + rb] = pk;
        }
      }
    int hstart = n0 >> 6;
    int hcnt = (N - n0) >> 6; if (hcnt > 2) hcnt = 2;
    int tot = hcnt * padrows * 128;
    for (int e = tid; e < tot; e += 256) {
      int hh = hstart + e / (padrows * 128);
      int rem = e % (padrows * 128);
      int j = rem >> 7, col = m0 + (rem & 127);
      VT[(size_t)(hh * 68 + 64 + j) * NN4 + col] = (j == 0) ? 0x3F80 : 0;
    }
  }
}

// --------- CVX split-K: Pb[z][4096][NF*16] (bf16) = cnt-slice @ Bt^T ---------
// 16 K-slices (512 blocks = 2/CU). 2-phase pipeline, B via global_load_lds
// with source-side XOR swizzle. (R7 champion version.)
template<int NF>
__global__ __launch_bounds__(256, 2) void k_cvxg(
    const float* __restrict__ cnt,
    const unsigned short* __restrict__ Bt,     // [NF*16][4096] bf16
    unsigned short* __restrict__ Pb) {
  constexpr int LDB = NF * 16;
  __shared__ unsigned short As[2][128 * 40];
  __shared__ unsigned short Bs[2][LDB * 32];
  const int tid = threadIdx.x, lane = tid & 63, wid = tid >> 6;
  const int hi = lane >> 4, lo = lane & 15;
  const int m0 = blockIdx.x * 128;
  const int kbeg = blockIdx.y << 8, kend = kbeg + 256;
  const int arow = tid >> 1, ak = (tid & 1) << 4;
  const int boff = (lo * 64 + hi * 16) ^ (((lo >> 1) & 3) << 4);

  f32x4 acc[2][NF];
#pragma unroll
  for (int i = 0; i < 2; ++i)
#pragma unroll
    for (int j = 0; j < NF; ++j) acc[i][j] = (f32x4){0.f, 0.f, 0.f, 0.f};

  f32x4 ar0, ar1, ar2, ar3;
  {
    const float* s = cnt + (size_t)(m0 + arow) * 4096 + kbeg + ak;
    ar0 = *(const f32x4*)(s);     ar1 = *(const f32x4*)(s + 4);
    ar2 = *(const f32x4*)(s + 8); ar3 = *(const f32x4*)(s + 12);
  }
  for (int c = wid; c < NF; c += 4) {
    int P = c * 1024 + lane * 16;
    int L = P ^ ((P >> 3) & 0x30);
    GLOAD16(Bt + (size_t)(L >> 6) * 4096 + kbeg + ((L & 63) >> 1),
            (char*)&Bs[0][0] + c * 1024);
  }
  *(ushort8*)&As[0][arow * 40 + ak]     = cvt8(ar0, ar1);
  *(ushort8*)&As[0][arow * 40 + ak + 8] = cvt8(ar2, ar3);
  asm volatile("s_waitcnt vmcnt(0)" ::: "memory");
  __syncthreads();

  for (int k0 = kbeg; k0 < kend; k0 += 32) {
    const int cur = ((k0 - kbeg) >> 5) & 1, nxt = cur ^ 1;
    const bool more = (k0 + 32 < kend);
    if (more) {
      const float* s = cnt + (size_t)(m0 + arow) * 4096 + (k0 + 32) + ak;
      ar0 = *(const f32x4*)(s);     ar1 = *(const f32x4*)(s + 4);
      ar2 = *(const f32x4*)(s + 8); ar3 = *(const f32x4*)(s + 12);
      for (int c = wid; c < NF; c += 4) {
        int P = c * 1024 + lane * 16;
        int L = P ^ ((P >> 3) & 0x30);
        GLOAD16(Bt + (size_t)(L >> 6) * 4096 + (k0 + 32) + ((L & 63) >> 1),
                (char*)&Bs[nxt][0] + c * 1024);
      }
    }
    short8 af0 = *(const short8*)&As[cur][(32 * wid + lo) * 40 + hi * 8];
    short8 af1 = *(const short8*)&As[cur][(32 * wid + 16 + lo) * 40 + hi * 8];
    __builtin_amdgcn_s_setprio(1);
#pragma unroll
    for (int j = 0; j < NF; ++j) {
      short8 bf = *(const short8*)((const char*)&Bs[cur][0] + j * 1024 + boff);
      acc[0][j] = __builtin_amdgcn_mfma_f32_16x16x32_bf16(af0, bf, acc[0][j], 0, 0, 0);
      acc[1][j] = __builtin_amdgcn_mfma_f32_16x16x32_bf16(af1, bf, acc[1][j], 0, 0, 0);
    }
    __builtin_amdgcn_s_setprio(0);
    if (more) {
      *(ushort8*)&As[nxt][arow * 40 + ak]     = cvt8(ar0, ar1);
      *(ushort8*)&As[nxt][arow * 40 + ak + 8] = cvt8(ar2, ar3);
    }
    asm volatile("s_waitcnt vmcnt(0)" ::: "memory");
    __syncthreads();
  }
  unsigned short* P = Pb + (size_t)blockIdx.y * 4096 * LDB;
#pragma unroll
  for (int i = 0; i < 2; ++i)
#pragma unroll
    for (int j = 0; j < NF; ++j)
#pragma unroll
      for (int reg = 0; reg < 4; ++reg) {
        int r = m0 + 32 * wid + 16 * i + 4 * hi + reg;
        P[(size_t)r * LDB + 16 * j + lo] = f2b(acc[i][j][reg]);
      }
}

// ---------- reduce bf16 split-K partials + transpose -> bf16 [orow][4096] ----------
__global__ __launch_bounds__(256) void k_tredB(const unsigned short* __restrict__ in, int ld,
                                               int nsl, unsigned short* __restrict__ out,
                                               int orow) {
  __shared__ float t[64][65];
  const int n0 = blockIdx.x << 6, d0 = blockIdx.y << 6;
  const int o  = threadIdx.x & 7;
  const int rr = threadIdx.x >> 3;
  const size_t pstride = (size_t)4096 * ld;
  const bool valid = (o * 8) < (ld - d0);
#pragma unroll
  for (int pass = 0; pass < 2; ++pass) {
    const int r = rr + (pass << 5);
    float a[8] = {0.f, 0.f, 0.f, 0.f, 0.f, 0.f, 0.f, 0.f};
    if (valid) {
      const unsigned short* p = in + (size_t)(n0 + r) * ld + d0 + o * 8;
      for (int z = 0; z < nsl; ++z) {
        ushort8 v = *(const ushort8*)(p + (size_t)z * pstride);
#pragma unroll
        for (int k = 0; k < 8; ++k) a[k] += b2f(v[k]);
      }
    }
#pragma unroll
    for (int k = 0; k < 8; ++k) t[o * 8 + k][r] = a[k];
  }
  __syncthreads();
  const int c = threadIdx.x & 63, r4 = threadIdx.x >> 6;
#pragma unroll
  for (int i = 0; i < 16; ++i) {
    int dr = r4 + (i << 2);
    if (d0 + dr < orow)
      out[(size_t)(d0 + dr) * 4096 + n0 + c] = f2b(t[dr][c]);
  }
}

// ---------------- fused GKAT attention: num = exp2(Q K^T) @ CVX^T ----------------
// (QSCALE pre-folded into Q). 256 threads / 4 waves. T14 async-stage, T5 setprio.
__global__ __launch_bounds__(256, 2) void k_attn(
    const unsigned short* __restrict__ Qg, const unsigned short* __restrict__ Kg,
    int ldqk, const unsigned short* __restrict__ CVg,
    unsigned short* __restrict__ Pb) {
  __shared__ unsigned short Ks[128 * 72];
  __shared__ unsigned short Cs[80 * 136];
  __shared__ unsigned short Es[128 * 136];     // byte ^= (row&7)<<5 swizzle
  const int tid = threadIdx.x, lane = tid & 63, wid = tid >> 6;
  const int hi = lane >> 4, lo = lane & 15;
  const int qb = blockIdx.x, h = blockIdx.y, sl = blockIdx.z;
  const int n0 = qb * 128;
  const int MS = 4096 / gridDim.z;
  const int m0beg = sl * MS;
  const int wr = (wid >> 1) << 6, wc = (wid & 1) << 6;

  short8 qf[4][2];
  const unsigned short* Qh = Qg + (size_t)h * 64;
#pragma unroll
  for (int j = 0; j < 4; ++j)
#pragma unroll
    for (int t = 0; t < 2; ++t)
      qf[j][t] = *(const short8*)(Qh + (size_t)(n0 + wc + 16 * j + lo) * ldqk + t * 32 + hi * 8);

  const unsigned short* CVh = CVg + (size_t)h * 68 * NN4;
  const unsigned short* Kh  = Kg + (size_t)h * 64;

  const int krow = tid >> 1, khalf = (tid & 1) << 5;
  int crdR[5], crdW[5], ccol[5];
#pragma unroll
  for (int k = 0; k < 5; ++k) {
    int c = tid + k * 256;
    int row = c >> 4;
    crdW[k] = row;
    crdR[k] = row < 68 ? row : 67;
    ccol[k] = (c & 15) << 3;
  }
  ushort8 krg[4], crg[5];

  auto LOADK = [&](int m0) {
    const unsigned short* src = Kh + (size_t)(m0 + krow) * ldqk + khalf;
    krg[0] = *(const ushort8*)(src);
    krg[1] = *(const ushort8*)(src + 8);
    krg[2] = *(const ushort8*)(src + 16);
    krg[3] = *(const ushort8*)(src + 24);
  };
  auto LOADC = [&](int m0) {
#pragma unroll
    for (int k = 0; k < 5; ++k)
      crg[k] = *(const ushort8*)(CVh + (size_t)crdR[k] * NN4 + m0 + ccol[k]);
  };
  auto WRITEK = [&]() {
    unsigned short* dp = &Ks[krow * 72 + khalf];
    *(ushort8*)(dp) = krg[0];      *(ushort8*)(dp + 8) = krg[1];
    *(ushort8*)(dp + 16) = krg[2]; *(ushort8*)(dp + 24) = krg[3];
  };
  auto WRITEC = [&]() {
#pragma unroll
    for (int k = 0; k < 5; ++k)
      *(ushort8*)&Cs[crdW[k] * 136 + ccol[k]] = crg[k];
  };

  f32x4 accn[2][5];
#pragma unroll
  for (int i = 0; i < 2; ++i)
#pragma unroll
    for (int j = 0; j < 5; ++j) accn[i][j] = (f32x4){0.f, 0.f, 0.f, 0.f};

  LOADK(m0beg); LOADC(m0beg);
  WRITEK(); WRITEC();
  __syncthreads();

  for (int mt = 0; mt < MS; mt += 128) {
    const int m0 = m0beg + mt;
    const bool more = (mt + 128) < MS;
    if (more) { LOADK(m0 + 128); LOADC(m0 + 128); }   // loads fly under compute
    // ---- QK^T ----
    short8 kf[4][2];
#pragma unroll
    for (int i = 0; i < 4; ++i)
#pragma unroll
      for (int t = 0; t < 2; ++t)
        kf[i][t] = *(const short8*)&Ks[(wr + 16 * i + lo) * 72 + t * 32 + hi * 8];
    f32x4 s[4][4];
#pragma unroll
    for (int i = 0; i < 4; ++i)
#pragma unroll
      for (int j = 0; j < 4; ++j) s[i][j] = (f32x4){0.f, 0.f, 0.f, 0.f};
    __builtin_amdgcn_s_setprio(1);
#pragma unroll
    for (int t = 0; t < 2; ++t)
#pragma unroll
      for (int i = 0; i < 4; ++i)
#pragma unroll
        for (int j = 0; j < 4; ++j)
          s[i][j] = __builtin_amdgcn_mfma_f32_16x16x32_bf16(kf[i][t], qf[j][t], s[i][j], 0, 0, 0);
    __builtin_amdgcn_s_setprio(0);
    // ---- E = exp2(S) -> Es (swizzled) ----
#pragma unroll
    for (int i = 0; i < 4; ++i)
#pragma unroll
      for (int j = 0; j < 4; ++j) {
        unsigned int u0 = (unsigned int)f2b(__builtin_amdgcn_exp2f(s[i][j][0])) |
                          ((unsigned int)f2b(__builtin_amdgcn_exp2f(s[i][j][1])) << 16);
        unsigned int u1 = (unsigned int)f2b(__builtin_amdgcn_exp2f(s[i][j][2])) |
                          ((unsigned int)f2b(__builtin_amdgcn_exp2f(s[i][j][3])) << 16);
        unsigned long long pk = (unsigned long long)u0 | ((unsigned long long)u1 << 32);
        int row = wc + 16 * j + lo;
        int byte = row * 272 + (wr + 16 * i + 4 * hi) * 2;
        *(unsigned long long*)((char*)Es + (byte ^ ((row & 7) << 5))) = pk;
      }
    __syncthreads();                         // A: Es ready, Ks consumed
    if (more) WRITEK();                      // Ks refill overlaps num phase
    // ---- num += E @ Cs^T ----
    __builtin_amdgcn_s_setprio(1);
#pragma unroll
    for (int t2 = 0; t2 < 4; ++t2) {
      int r0 = 32 * wid + lo, r1 = r0 + 16;
      int cb = (t2 * 32 + hi * 8) * 2;
      short8 ea0 = *(const short8*)((const char*)Es + ((r0 * 272 + cb) ^ ((r0 & 7) << 5)));
      short8 ea1 = *(const short8*)((const char*)Es + ((r1 * 272 + cb) ^ ((r1 & 7) << 5)));
      short8 cbv[5];
#pragma unroll
      for (int j2 = 0; j2 < 5; ++j2)
        cbv[j2] = *(const short8*)&Cs[(16 * j2 + lo) * 136 + t2 * 32 + hi * 8];
#pragma unroll
      for (int j2 = 0; j2 < 5; ++j2) {
        accn[0][j2] = __builtin_amdgcn_mfma_f32_16x16x32_bf16(ea0, cbv[j2], accn[0][j2], 0, 0, 0);
        accn[1][j2] = __builtin_amdgcn_mfma_f32_16x16x32_bf16(ea1, cbv[j2], accn[1][j2], 0, 0, 0);
      }
    }
    __builtin_amdgcn_s_setprio(0);
    __syncthreads();                         // B: Cs consumed
    if (more) { WRITEC(); __syncthreads(); } // C: Cs(t+1) visible
  }
  unsigned short* P = Pb + (((size_t)h * gridDim.x + qb) * gridDim.z + sl) * (128 * 80);
#pragma unroll
  for (int i2 = 0; i2 < 2; ++i2)
#pragma unroll
    for (int j2 = 0; j2 < 5; ++j2)
#pragma unroll
      for (int reg = 0; reg < 4; ++reg) {
        int r = 32 * wid + 16 * i2 + 4 * hi + reg;
        int c = 16 * j2 + lo;
        P[(size_t)r * 80 + c] = f2b(accn[i2][j2][reg]);
      }
}

// ---------- merge slices: x = num/(den+1e-9), elu, bf16 store ----------
__global__ void k_fin2(const unsigned short* __restrict__ parts, int nsl,
                       unsigned short* __restrict__ hb, int ldh) {
  int idx = blockIdx.x * 256 + threadIdx.x;
  int d = idx & 63, r = (idx >> 6) & 4095, h = idx >> 18;
  size_t b0 = ((size_t)(h * 32 + (r >> 7)) * nsl) * 10240 + (size_t)(r & 127) * 80;
  float nm = 0.f, dn = 0.f;
  for (int sl = 0; sl < nsl; ++sl) {
    const unsigned short* p = parts + b0 + (size_t)sl * 10240;
    nm += b2f(p[d]); dn += b2f(p[64]);
  }
  float x = nm / (dn + 1e-9f);
  x = x > 0.f ? x : expm1f(x);
  hb[(size_t)r * ldh + h * 64 + d] = f2b(x);
}

// ---------- layer-2 finalize + classifier ----------
__global__ __launch_bounds__(256) void k_fincls(const unsigned short* __restrict__ parts,
                                                int nsl, const float* __restrict__ Wc,
                                                const float* __restrict__ bc,
                                                float* __restrict__ out) {
  int r = blockIdx.x * 4 + (threadIdx.x >> 6);
  int d = threadIdx.x & 63;
  size_t b0 = ((size_t)(r >> 7) * nsl) * 10240 + (size_t)(r & 127) * 80;
  float nm = 0.f, dn = 0.f;
  for (int sl = 0; sl < nsl; ++sl) {
    const unsigned short* p = parts + b0 + (size_t)sl * 10240;
    nm += b2f(p[d]); dn += b2f(p[64]);
  }
  float x = nm / (dn + 1e-9f);
  x = x > 0.f ? x : expm1f(x);
#pragma unroll
  for (int cl = 0; cl < 10; ++cl) {
    float v = x * Wc[cl * 64 + d];
#pragma unroll
    for (int off = 32; off; off >>= 1) v += __shfl_xor(v, off);
    if (d == 0) out[(size_t)r * 10 + cl] = v + bc[cl];
  }
}

extern "C" void kernel_launch(void* const* d_in, const int* in_sizes, int n_in,
                              void* d_out, int out_size, void* d_ws, size_t ws_size,
                              hipStream_t stream) {
  (void)in_sizes; (void)n_in; (void)out_size; (void)ws_size;
  const float* feats    = (const float*)d_in[0];
  const float* counting = (const float*)d_in[1];
  const float* Wq1 = (const float*)d_in[2];
  const float* Wk1 = (const float*)d_in[3];
  const float* Wv1 = (const float*)d_in[4];
  const float* Wq2 = (const float*)d_in[5];
  const float* Wk2 = (const float*)d_in[6];
  const float* Wv2 = (const float*)d_in[7];
  const float* Wc  = (const float*)d_in[8];
  const float* bc  = (const float*)d_in[9];
  float* out = (float*)d_out;

  char* w = (char*)d_ws;
  size_t off = 0;
  auto alloc = [&](size_t bytes) { void* p = w + off; off += (bytes + 255) & ~(size_t)255; return p; };
  unsigned short* hnb    = (unsigned short*)alloc((size_t)4096 * 512 * 2);
  unsigned short* Q1b    = (unsigned short*)alloc((size_t)4096 * 256 * 2);
  unsigned short* K1b    = (unsigned short*)alloc((size_t)4096 * 256 * 2);
  unsigned short* V1xT   = (unsigned short*)alloc((size_t)272 * 4096 * 2);
  unsigned short* CVX1Tb = (unsigned short*)alloc((size_t)272 * 4096 * 2);
  unsigned short* h1b    = (unsigned short*)alloc((size_t)4096 * 256 * 2);
  unsigned short* Q2b    = (unsigned short*)alloc((size_t)4096 * 64 * 2);
  unsigned short* K2b    = (unsigned short*)alloc((size_t)4096 * 64 * 2);
  unsigned short* V2xT   = (unsigned short*)alloc((size_t)80 * 4096 * 2);
  unsigned short* CVX2Tb = (unsigned short*)alloc((size_t)68 * 4096 * 2);
  unsigned short* big    = (unsigned short*)alloc((size_t)36 * 1024 * 1024);

  k_norm<<<1024, 256, 0, stream>>>(feats, hnb);

  // layer-1 Q/K/V (Q prescaled by 0.125*log2e; V transposed + ones rows)
  k_projqkv<<<dim3(32, 6), 256, 0, stream>>>(hnb, 512, Wq1, Wk1, Wv1, 256, 2,
                                             Q1b, K1b, V1xT, 4, QSCALE);
  // CVX1 = counting @ [V1|1]
  k_cvxg<17><<<dim3(32, 16), 256, 0, stream>>>(counting, V1xT, big);
  k_tredB<<<dim3(64, 5), 256, 0, stream>>>(big, 272, 16, CVX1Tb, 272);
  // layer-1 fused attention + merge
  k_attn<<<dim3(32, 4, 4), 256, 0, stream>>>(Q1b, K1b, 256, CVX1Tb, big);
  k_fin2<<<4096, 256, 0, stream>>>(big, 4, h1b, 256);

  // layer-2 Q/K/V
  k_projqkv<<<dim3(32, 3), 256, 0, stream>>>(h1b, 256, Wq2, Wk2, Wv2, 64, 1,
                                             Q2b, K2b, V2xT, 16, QSCALE);
  // CVX2
  k_cvxg<5><<<dim3(32, 16), 256, 0, stream>>>(counting, V2xT, big);
  k_tredB<<<dim3(64, 2), 256, 0, stream>>>(big, 80, 16, CVX2Tb, 68);
  // layer-2 fused attention + finalize + classifier
  k_attn<<<dim3(32, 1, 16), 256, 0, stream>>>(Q2b, K2b, 64, CVX2Tb, big);
  k_fincls<<<1024, 256, 0, stream>>>(big, 16, Wc, bc, out);
}